// Round 1
// baseline (401.177 us; speedup 1.0000x reference)
//
#include <hip/hip_runtime.h>
#include <hip/hip_bf16.h>

typedef __attribute__((ext_vector_type(4))) float  f32x4;
typedef __attribute__((ext_vector_type(8))) short  short8;
typedef __attribute__((ext_vector_type(4))) short  short4v;

__device__ __forceinline__ unsigned short f32_to_bf16(float f) {
    union { float f; unsigned u; } v; v.f = f;
    unsigned r = v.u + 0x7FFFu + ((v.u >> 16) & 1u);   // RNE
    return (unsigned short)(r >> 16);
}
__device__ __forceinline__ float bf16_to_f32(unsigned short h) {
    union { unsigned u; float f; } v; v.u = ((unsigned)h) << 16; return v.f;
}
__device__ __forceinline__ void gload_lds16(const void* g, void* l) {
    __builtin_amdgcn_global_load_lds(
        (const __attribute__((address_space(1))) unsigned int*)g,
        (__attribute__((address_space(3))) unsigned int*)l,
        16, 0, 0);
}

// ---------------- transpose + fp32->bf16 convert ----------------
// src fp32 [R][Cin] row-major  ->  dst bf16 [Cpad][R]; rows c in [Cin,Cpad) are zero.
__global__ __launch_bounds__(256) void transpose_to_bf16(
    const float* __restrict__ src, unsigned short* __restrict__ dst,
    int R, int Cin, int Cpad) {
    __shared__ float tile[32][33];
    const int tx = threadIdx.x;          // 0..31
    const int ty = threadIdx.y;          // 0..7
    const int c0 = blockIdx.x * 32;
    const int r0 = blockIdx.y * 32;
#pragma unroll
    for (int i = 0; i < 4; ++i) {
        int r = r0 + ty + i * 8;
        int c = c0 + tx;
        float v = 0.f;
        if (r < R && c < Cin) v = src[(size_t)r * Cin + c];
        tile[ty + i * 8][tx] = v;
    }
    __syncthreads();
#pragma unroll
    for (int i = 0; i < 4; ++i) {
        int c = c0 + ty + i * 8;
        int r = r0 + tx;
        if (c < Cpad && r < R)
            dst[(size_t)c * R + r] = f32_to_bf16(tile[tx][ty + i * 8]);
    }
}

// ---------------- bias[c] = -sum_d mean[d] * Mt[c][d] ----------------
__global__ __launch_bounds__(256) void bias_kernel(
    const float* __restrict__ mean, const unsigned short* __restrict__ Mt,
    float* __restrict__ bias, int D) {
    const int c = blockIdx.x;
    const unsigned short* row = Mt + (size_t)c * D;
    float s = 0.f;
    for (int d0 = threadIdx.x * 8; d0 < D; d0 += 256 * 8) {
        short4v h0 = *(const short4v*)&row[d0];
        short4v h1 = *(const short4v*)&row[d0 + 4];
        f32x4  m0 = *(const f32x4*)&mean[d0];
        f32x4  m1 = *(const f32x4*)&mean[d0 + 4];
#pragma unroll
        for (int j = 0; j < 4; ++j) {
            s += bf16_to_f32((unsigned short)h0[j]) * m0[j];
            s += bf16_to_f32((unsigned short)h1[j]) * m1[j];
        }
    }
#pragma unroll
    for (int off = 32; off > 0; off >>= 1) s += __shfl_down(s, off);
    __shared__ float red[4];
    const int lane = threadIdx.x & 63, w = threadIdx.x >> 6;
    if (lane == 0) red[w] = s;
    __syncthreads();
    if (threadIdx.x == 0) bias[c] = -(red[0] + red[1] + red[2] + red[3]);
}

// ---------------- GEMM1: C_bf16[M][N] = A[M][K] * Bt[N][K]^T (all bf16) ----------------
#define BM 128
#define BN 128
#define BK 64

__global__ __launch_bounds__(256) void gemm_bt_bf16out(
    const unsigned short* __restrict__ A,   // [M][K] bf16
    const unsigned short* __restrict__ Bt,  // [N][K] bf16
    unsigned short* __restrict__ C,         // [M][N] bf16
    int M, int N, int K) {
    __shared__ unsigned short As[BM * BK];
    __shared__ unsigned short Bs[BN * BK];
    const int t = threadIdx.x;
    const int lane = t & 63;
    const int w = t >> 6;
    const int wr = w >> 1, wc = w & 1;
    const int lr = lane & 15, hi = lane >> 4;
    const int row0 = blockIdx.y * BM;
    const int col0 = blockIdx.x * BN;

    f32x4 acc[4][4];
#pragma unroll
    for (int m = 0; m < 4; ++m)
#pragma unroll
        for (int n = 0; n < 4; ++n) acc[m][n] = (f32x4){0.f, 0.f, 0.f, 0.f};

    const int ar = t >> 3;          // 0..31
    const int ac = (t & 7) * 8;     // element col, 16B granule

    for (int k0 = 0; k0 < K; k0 += BK) {
#pragma unroll
        for (int i = 0; i < 4; ++i) {
            int r = i * 32 + ar;
            gload_lds16(A + (size_t)(row0 + r) * K + (k0 + ac), &As[r * BK + ac]);
            gload_lds16(Bt + (size_t)(col0 + r) * K + (k0 + ac), &Bs[r * BK + ac]);
        }
        __syncthreads();
#pragma unroll
        for (int s = 0; s < 2; ++s) {
            short8 a[4], b[4];
#pragma unroll
            for (int m = 0; m < 4; ++m)
                a[m] = *(const short8*)&As[(wr * 64 + m * 16 + lr) * BK + s * 32 + hi * 8];
#pragma unroll
            for (int n = 0; n < 4; ++n)
                b[n] = *(const short8*)&Bs[(wc * 64 + n * 16 + lr) * BK + s * 32 + hi * 8];
#pragma unroll
            for (int m = 0; m < 4; ++m)
#pragma unroll
                for (int n = 0; n < 4; ++n)
                    acc[m][n] = __builtin_amdgcn_mfma_f32_16x16x32_bf16(a[m], b[n], acc[m][n], 0, 0, 0);
        }
        __syncthreads();
    }
#pragma unroll
    for (int m = 0; m < 4; ++m) {
        int rg = row0 + wr * 64 + m * 16 + hi * 4;
#pragma unroll
        for (int n = 0; n < 4; ++n) {
            int cg = col0 + wc * 64 + n * 16 + lr;
#pragma unroll
            for (int j = 0; j < 4; ++j)
                C[(size_t)(rg + j) * N + cg] = f32_to_bf16(acc[m][n][j]);
        }
    }
}

// ---------------- GEMM2: out[M][Nout] = A_f32[M][K] * Bt_bf16[N][K]^T + bias ----------------
__global__ __launch_bounds__(256) void gemm2_f32a(
    const float* __restrict__ A,            // feats [M][K] fp32
    const unsigned short* __restrict__ Bt,  // Mt [N][K] bf16
    const float* __restrict__ bias,         // [N]
    float* __restrict__ out,                // [M][Nout] fp32
    int M, int N, int K, int Nout) {
    __shared__ unsigned short As[BM * BK];
    __shared__ unsigned short Bs[BN * BK];
    const int t = threadIdx.x;
    const int lane = t & 63;
    const int w = t >> 6;
    const int wr = w >> 1, wc = w & 1;
    const int lr = lane & 15, hi = lane >> 4;
    const int row0 = blockIdx.y * BM;
    const int col0 = blockIdx.x * BN;

    f32x4 acc[4][4];
#pragma unroll
    for (int m = 0; m < 4; ++m)
#pragma unroll
        for (int n = 0; n < 4; ++n) acc[m][n] = (f32x4){0.f, 0.f, 0.f, 0.f};

    const int br = t >> 3;
    const int bc = (t & 7) * 8;

    for (int k0 = 0; k0 < K; k0 += BK) {
        // B: async bf16 -> LDS
#pragma unroll
        for (int i = 0; i < 4; ++i) {
            int r = i * 32 + br;
            gload_lds16(Bt + (size_t)(col0 + r) * K + (k0 + bc), &Bs[r * BK + bc]);
        }
        // A: reg-stage fp32 -> bf16 -> LDS
#pragma unroll
        for (int i = 0; i < 8; ++i) {
            int e = i * 1024 + t * 4;
            int r = e >> 6;
            int c = e & 63;
            f32x4 v = *(const f32x4*)(A + (size_t)(row0 + r) * K + (k0 + c));
            short4v h;
            h[0] = (short)f32_to_bf16(v[0]);
            h[1] = (short)f32_to_bf16(v[1]);
            h[2] = (short)f32_to_bf16(v[2]);
            h[3] = (short)f32_to_bf16(v[3]);
            *(short4v*)&As[r * BK + c] = h;
        }
        __syncthreads();
#pragma unroll
        for (int s = 0; s < 2; ++s) {
            short8 a[4], b[4];
#pragma unroll
            for (int m = 0; m < 4; ++m)
                a[m] = *(const short8*)&As[(wr * 64 + m * 16 + lr) * BK + s * 32 + hi * 8];
#pragma unroll
            for (int n = 0; n < 4; ++n)
                b[n] = *(const short8*)&Bs[(wc * 64 + n * 16 + lr) * BK + s * 32 + hi * 8];
#pragma unroll
            for (int m = 0; m < 4; ++m)
#pragma unroll
                for (int n = 0; n < 4; ++n)
                    acc[m][n] = __builtin_amdgcn_mfma_f32_16x16x32_bf16(a[m], b[n], acc[m][n], 0, 0, 0);
        }
        __syncthreads();
    }
#pragma unroll
    for (int m = 0; m < 4; ++m) {
        int rg = row0 + wr * 64 + m * 16 + hi * 4;
#pragma unroll
        for (int n = 0; n < 4; ++n) {
            int cg = col0 + wc * 64 + n * 16 + lr;
            if (cg < Nout) {
                float bv = bias[cg];
#pragma unroll
                for (int j = 0; j < 4; ++j)
                    out[(size_t)(rg + j) * Nout + cg] = acc[m][n][j] + bv;
            }
        }
    }
}

extern "C" void kernel_launch(void* const* d_in, const int* in_sizes, int n_in,
                              void* d_out, int out_size, void* d_ws, size_t ws_size,
                              hipStream_t stream) {
    const float* feats = (const float*)d_in[0];   // [8192][8192]
    const float* mean  = (const float*)d_in[1];   // [8192]
    const float* comp  = (const float*)d_in[2];   // [2048][8192]
    const float* W     = (const float*)d_in[3];   // [2048][1000]
    float* out = (float*)d_out;                   // [8192][1000]

    const int N = 8192, D = 8192, Kp = 2048, C = 1000, Cp = 1024;

    char* ws = (char*)d_ws;
    unsigned short* Wt    = (unsigned short*)ws;                             // [Cp][Kp] bf16
    size_t off = (size_t)Cp * Kp * 2;
    unsigned short* compT = (unsigned short*)(ws + off);                     // [D][Kp] bf16
    off += (size_t)D * Kp * 2;
    unsigned short* Mt    = (unsigned short*)(ws + off);                     // [Cp][D] bf16
    off += (size_t)Cp * D * 2;
    float* bias           = (float*)(ws + off);                              // [Cp] f32

    dim3 tb(32, 8);
    // Wt[c][k] = bf16(W[k][c]), zero rows c in [1000,1024)
    transpose_to_bf16<<<dim3(Cp / 32, Kp / 32), tb, 0, stream>>>(W, Wt, Kp, C, Cp);
    // compT[d][k] = bf16(comp[k][d])
    transpose_to_bf16<<<dim3(D / 32, Kp / 32), tb, 0, stream>>>(comp, compT, Kp, D, D);
    // Mt[c][d] = sum_k Wt[c][k]*compT[d][k]
    gemm_bt_bf16out<<<dim3(D / BN, Cp / BM), 256, 0, stream>>>(Wt, compT, Mt, Cp, D, Kp);
    // bias[c] = -sum_d mean[d]*Mt[c][d]
    bias_kernel<<<Cp, 256, 0, stream>>>(mean, Mt, bias, D);
    // out[n][c] = sum_d feats[n][d]*Mt[c][d] + bias[c]
    gemm2_f32a<<<dim3(Cp / BN, N / BM), 256, 0, stream>>>(feats, Mt, bias, out, N, Cp, D, C);
}

// Round 2
// 383.721 us; speedup vs baseline: 1.0455x; 1.0455x over previous
//
#include <hip/hip_runtime.h>
#include <hip/hip_bf16.h>

typedef __attribute__((ext_vector_type(4))) float  f32x4;
typedef __attribute__((ext_vector_type(8))) short  short8;
typedef __attribute__((ext_vector_type(4))) short  short4v;

__device__ __forceinline__ unsigned short f32_to_bf16(float f) {
    union { float f; unsigned u; } v; v.f = f;
    unsigned r = v.u + 0x7FFFu + ((v.u >> 16) & 1u);   // RNE
    return (unsigned short)(r >> 16);
}
__device__ __forceinline__ float bf16_to_f32(unsigned short h) {
    union { unsigned u; float f; } v; v.u = ((unsigned)h) << 16; return v.f;
}
__device__ __forceinline__ void gload_lds16(const void* g, void* l) {
    __builtin_amdgcn_global_load_lds(
        (const __attribute__((address_space(1))) unsigned int*)g,
        (__attribute__((address_space(3))) unsigned int*)l,
        16, 0, 0);
}

// ---------------- transpose + fp32->bf16 convert ----------------
__global__ __launch_bounds__(256) void transpose_to_bf16(
    const float* __restrict__ src, unsigned short* __restrict__ dst,
    int R, int Cin, int Cpad) {
    __shared__ float tile[32][33];
    const int tx = threadIdx.x, ty = threadIdx.y;
    const int c0 = blockIdx.x * 32, r0 = blockIdx.y * 32;
#pragma unroll
    for (int i = 0; i < 4; ++i) {
        int r = r0 + ty + i * 8, c = c0 + tx;
        float v = 0.f;
        if (r < R && c < Cin) v = src[(size_t)r * Cin + c];
        tile[ty + i * 8][tx] = v;
    }
    __syncthreads();
#pragma unroll
    for (int i = 0; i < 4; ++i) {
        int c = c0 + ty + i * 8, r = r0 + tx;
        if (c < Cpad && r < R)
            dst[(size_t)c * R + r] = f32_to_bf16(tile[tx][ty + i * 8]);
    }
}

// ---------------- flat fp32 -> bf16 convert (grid-stride, vectorized) ----------------
__global__ __launch_bounds__(256) void convert_f32_bf16(
    const float* __restrict__ src, unsigned short* __restrict__ dst, size_t n) {
    size_t i = ((size_t)blockIdx.x * 256 + threadIdx.x) * 8;
    const size_t stride = (size_t)gridDim.x * 256 * 8;
    for (; i < n; i += stride) {
        f32x4 v0 = *(const f32x4*)(src + i);
        f32x4 v1 = *(const f32x4*)(src + i + 4);
        short8 h;
#pragma unroll
        for (int j = 0; j < 4; ++j) h[j] = (short)f32_to_bf16(v0[j]);
#pragma unroll
        for (int j = 0; j < 4; ++j) h[4 + j] = (short)f32_to_bf16(v1[j]);
        *(short8*)(dst + i) = h;
    }
}

// ---------------- bias[c] = -sum_d mean[d] * Mt[c][d] ----------------
__global__ __launch_bounds__(256) void bias_kernel(
    const float* __restrict__ mean, const unsigned short* __restrict__ Mt,
    float* __restrict__ bias, int D) {
    const int c = blockIdx.x;
    const unsigned short* row = Mt + (size_t)c * D;
    float s = 0.f;
    for (int d0 = threadIdx.x * 8; d0 < D; d0 += 256 * 8) {
        short4v h0 = *(const short4v*)&row[d0];
        short4v h1 = *(const short4v*)&row[d0 + 4];
        f32x4  m0 = *(const f32x4*)&mean[d0];
        f32x4  m1 = *(const f32x4*)&mean[d0 + 4];
#pragma unroll
        for (int j = 0; j < 4; ++j) {
            s += bf16_to_f32((unsigned short)h0[j]) * m0[j];
            s += bf16_to_f32((unsigned short)h1[j]) * m1[j];
        }
    }
#pragma unroll
    for (int off = 32; off > 0; off >>= 1) s += __shfl_down(s, off);
    __shared__ float red[4];
    const int lane = threadIdx.x & 63, w = threadIdx.x >> 6;
    if (lane == 0) red[w] = s;
    __syncthreads();
    if (threadIdx.x == 0) bias[c] = -(red[0] + red[1] + red[2] + red[3]);
}

#define BM 128
#define BN 128
#define BK 64

// ---------------- GEMM1: Mt[M][N] (bf16) = A[M][K] * Bt[N][K]^T, bf16 in ----------------
// grid 1D = (M/BM)*(N/BN), chunked-XCD swizzled; decode: col = swz>>3, row = swz&7
// (consecutive swz share the same Bt panel -> same XCD L2)
__global__ __launch_bounds__(256) void gemm_bt_bf16out(
    const unsigned short* __restrict__ A, const unsigned short* __restrict__ Bt,
    unsigned short* __restrict__ C, int M, int N, int K) {
    const int nwg = gridDim.x;
    const int cpx = nwg >> 3;
    const int bid = blockIdx.x;
    const int swz = (bid & 7) * cpx + (bid >> 3);
    const int row0 = (swz & 7) * BM;
    const int col0 = (swz >> 3) * BN;

    __shared__ unsigned short As[BM * BK];
    __shared__ unsigned short Bs[BN * BK];
    const int t = threadIdx.x;
    const int lane = t & 63, w = t >> 6;
    const int wr = w >> 1, wc = w & 1;
    const int lr = lane & 15, hi = lane >> 4;

    f32x4 acc[4][4];
#pragma unroll
    for (int m = 0; m < 4; ++m)
#pragma unroll
        for (int n = 0; n < 4; ++n) acc[m][n] = (f32x4){0.f, 0.f, 0.f, 0.f};

    const int ar = t >> 3;
    const int ac = (t & 7) * 8;

    for (int k0 = 0; k0 < K; k0 += BK) {
#pragma unroll
        for (int i = 0; i < 4; ++i) {
            int r = i * 32 + ar;
            gload_lds16(A + (size_t)(row0 + r) * K + (k0 + ac), &As[r * BK + ac]);
            gload_lds16(Bt + (size_t)(col0 + r) * K + (k0 + ac), &Bs[r * BK + ac]);
        }
        __syncthreads();
#pragma unroll
        for (int s = 0; s < 2; ++s) {
            short8 a[4], b[4];
#pragma unroll
            for (int m = 0; m < 4; ++m)
                a[m] = *(const short8*)&As[(wr * 64 + m * 16 + lr) * BK + s * 32 + hi * 8];
#pragma unroll
            for (int n = 0; n < 4; ++n)
                b[n] = *(const short8*)&Bs[(wc * 64 + n * 16 + lr) * BK + s * 32 + hi * 8];
#pragma unroll
            for (int m = 0; m < 4; ++m)
#pragma unroll
                for (int n = 0; n < 4; ++n)
                    acc[m][n] = __builtin_amdgcn_mfma_f32_16x16x32_bf16(a[m], b[n], acc[m][n], 0, 0, 0);
        }
        __syncthreads();
    }
#pragma unroll
    for (int m = 0; m < 4; ++m) {
        int rg = row0 + wr * 64 + m * 16 + hi * 4;
#pragma unroll
        for (int n = 0; n < 4; ++n) {
            int cg = col0 + wc * 64 + n * 16 + lr;
#pragma unroll
            for (int j = 0; j < 4; ++j)
                C[(size_t)(rg + j) * N + cg] = f32_to_bf16(acc[m][n][j]);
        }
    }
}

// ---------------- GEMM2-A (big ws): out = featsB(bf16)[M][K] * Mt[N][K]^T + bias ----------------
// decode: row = swz>>3, col = swz&7 (consecutive swz share the same A panel)
__global__ __launch_bounds__(256) void gemm2_bf16a(
    const unsigned short* __restrict__ A, const unsigned short* __restrict__ Bt,
    const float* __restrict__ bias, float* __restrict__ out,
    int M, int N, int K, int Nout) {
    const int nwg = gridDim.x;
    const int cpx = nwg >> 3;
    const int bid = blockIdx.x;
    const int swz = (bid & 7) * cpx + (bid >> 3);
    const int row0 = (swz >> 3) * BM;
    const int col0 = (swz & 7) * BN;

    __shared__ unsigned short As[BM * BK];
    __shared__ unsigned short Bs[BN * BK];
    const int t = threadIdx.x;
    const int lane = t & 63, w = t >> 6;
    const int wr = w >> 1, wc = w & 1;
    const int lr = lane & 15, hi = lane >> 4;

    f32x4 acc[4][4];
#pragma unroll
    for (int m = 0; m < 4; ++m)
#pragma unroll
        for (int n = 0; n < 4; ++n) acc[m][n] = (f32x4){0.f, 0.f, 0.f, 0.f};

    const int ar = t >> 3;
    const int ac = (t & 7) * 8;

    for (int k0 = 0; k0 < K; k0 += BK) {
#pragma unroll
        for (int i = 0; i < 4; ++i) {
            int r = i * 32 + ar;
            gload_lds16(A + (size_t)(row0 + r) * K + (k0 + ac), &As[r * BK + ac]);
            gload_lds16(Bt + (size_t)(col0 + r) * K + (k0 + ac), &Bs[r * BK + ac]);
        }
        __syncthreads();
#pragma unroll
        for (int s = 0; s < 2; ++s) {
            short8 a[4], b[4];
#pragma unroll
            for (int m = 0; m < 4; ++m)
                a[m] = *(const short8*)&As[(wr * 64 + m * 16 + lr) * BK + s * 32 + hi * 8];
#pragma unroll
            for (int n = 0; n < 4; ++n)
                b[n] = *(const short8*)&Bs[(wc * 64 + n * 16 + lr) * BK + s * 32 + hi * 8];
#pragma unroll
            for (int m = 0; m < 4; ++m)
#pragma unroll
                for (int n = 0; n < 4; ++n)
                    acc[m][n] = __builtin_amdgcn_mfma_f32_16x16x32_bf16(a[m], b[n], acc[m][n], 0, 0, 0);
        }
        __syncthreads();
    }
#pragma unroll
    for (int m = 0; m < 4; ++m) {
        int rg = row0 + wr * 64 + m * 16 + hi * 4;
#pragma unroll
        for (int n = 0; n < 4; ++n) {
            int cg = col0 + wc * 64 + n * 16 + lr;
            if (cg < Nout) {
                float bv = bias[cg];
#pragma unroll
                for (int j = 0; j < 4; ++j)
                    out[(size_t)(rg + j) * Nout + cg] = acc[m][n][j] + bv;
            }
        }
    }
}

// ---------------- GEMM2-B (fallback): fp32 A reg-staged, swizzled ----------------
__global__ __launch_bounds__(256) void gemm2_f32a(
    const float* __restrict__ A, const unsigned short* __restrict__ Bt,
    const float* __restrict__ bias, float* __restrict__ out,
    int M, int N, int K, int Nout) {
    const int nwg = gridDim.x;
    const int cpx = nwg >> 3;
    const int bid = blockIdx.x;
    const int swz = (bid & 7) * cpx + (bid >> 3);
    const int row0 = (swz >> 3) * BM;
    const int col0 = (swz & 7) * BN;

    __shared__ unsigned short As[BM * BK];
    __shared__ unsigned short Bs[BN * BK];
    const int t = threadIdx.x;
    const int lane = t & 63, w = t >> 6;
    const int wr = w >> 1, wc = w & 1;
    const int lr = lane & 15, hi = lane >> 4;

    f32x4 acc[4][4];
#pragma unroll
    for (int m = 0; m < 4; ++m)
#pragma unroll
        for (int n = 0; n < 4; ++n) acc[m][n] = (f32x4){0.f, 0.f, 0.f, 0.f};

    const int br = t >> 3;
    const int bc = (t & 7) * 8;

    for (int k0 = 0; k0 < K; k0 += BK) {
#pragma unroll
        for (int i = 0; i < 4; ++i) {
            int r = i * 32 + br;
            gload_lds16(Bt + (size_t)(col0 + r) * K + (k0 + bc), &Bs[r * BK + bc]);
        }
#pragma unroll
        for (int i = 0; i < 8; ++i) {
            int e = i * 1024 + t * 4;
            int r = e >> 6, c = e & 63;
            f32x4 v = *(const f32x4*)(A + (size_t)(row0 + r) * K + (k0 + c));
            short4v h;
            h[0] = (short)f32_to_bf16(v[0]);
            h[1] = (short)f32_to_bf16(v[1]);
            h[2] = (short)f32_to_bf16(v[2]);
            h[3] = (short)f32_to_bf16(v[3]);
            *(short4v*)&As[r * BK + c] = h;
        }
        __syncthreads();
#pragma unroll
        for (int s = 0; s < 2; ++s) {
            short8 a[4], b[4];
#pragma unroll
            for (int m = 0; m < 4; ++m)
                a[m] = *(const short8*)&As[(wr * 64 + m * 16 + lr) * BK + s * 32 + hi * 8];
#pragma unroll
            for (int n = 0; n < 4; ++n)
                b[n] = *(const short8*)&Bs[(wc * 64 + n * 16 + lr) * BK + s * 32 + hi * 8];
#pragma unroll
            for (int m = 0; m < 4; ++m)
#pragma unroll
                for (int n = 0; n < 4; ++n)
                    acc[m][n] = __builtin_amdgcn_mfma_f32_16x16x32_bf16(a[m], b[n], acc[m][n], 0, 0, 0);
        }
        __syncthreads();
    }
#pragma unroll
    for (int m = 0; m < 4; ++m) {
        int rg = row0 + wr * 64 + m * 16 + hi * 4;
#pragma unroll
        for (int n = 0; n < 4; ++n) {
            int cg = col0 + wc * 64 + n * 16 + lr;
            if (cg < Nout) {
                float bv = bias[cg];
#pragma unroll
                for (int j = 0; j < 4; ++j)
                    out[(size_t)(rg + j) * Nout + cg] = acc[m][n][j] + bv;
            }
        }
    }
}

extern "C" void kernel_launch(void* const* d_in, const int* in_sizes, int n_in,
                              void* d_out, int out_size, void* d_ws, size_t ws_size,
                              hipStream_t stream) {
    const float* feats = (const float*)d_in[0];   // [8192][8192]
    const float* mean  = (const float*)d_in[1];   // [8192]
    const float* comp  = (const float*)d_in[2];   // [2048][8192]
    const float* W     = (const float*)d_in[3];   // [2048][1000]
    float* out = (float*)d_out;                   // [8192][1000]

    const int N = 8192, D = 8192, Kp = 2048, C = 1000, Cp = 1024;

    char* ws = (char*)d_ws;
    unsigned short* Wt    = (unsigned short*)ws;                  // [Cp][Kp]
    size_t off = (size_t)Cp * Kp * 2;
    unsigned short* compT = (unsigned short*)(ws + off);          // [D][Kp]
    off += (size_t)D * Kp * 2;
    unsigned short* Mt    = (unsigned short*)(ws + off);          // [Cp][D]
    off += (size_t)Cp * D * 2;
    float* bias           = (float*)(ws + off);                   // [Cp]
    off += 4096;
    unsigned short* featsB = (unsigned short*)(ws + off);         // [N][D] bf16
    const size_t need_big = off + (size_t)N * D * 2;

    dim3 tb(32, 8);
    transpose_to_bf16<<<dim3(Cp / 32, Kp / 32), tb, 0, stream>>>(W, Wt, Kp, C, Cp);
    transpose_to_bf16<<<dim3(D / 32, Kp / 32), tb, 0, stream>>>(comp, compT, Kp, D, D);
    gemm_bt_bf16out<<<(Cp / BM) * (D / BN), 256, 0, stream>>>(Wt, compT, Mt, Cp, D, Kp);
    bias_kernel<<<Cp, 256, 0, stream>>>(mean, Mt, bias, D);

    if (ws_size >= need_big) {
        convert_f32_bf16<<<2048, 256, 0, stream>>>(feats, featsB, (size_t)N * D);
        gemm2_bf16a<<<(N / BM) * (Cp / BN), 256, 0, stream>>>(featsB, Mt, bias, out, N, Cp, D, C);
    } else {
        gemm2_f32a<<<(N / BM) * (Cp / BN), 256, 0, stream>>>(feats, Mt, bias, out, N, Cp, D, C);
    }
}